// Round 2
// baseline (291.510 us; speedup 1.0000x reference)
//
#include <hip/hip_runtime.h>

// GCN 2-layer on MI355X — Round 12: sort pipeline unchanged; aggregation
// switched from 4-lanes-per-node (R11: wave ran at the speed of its
// slowest lane, ~Poisson(8) run lengths -> max-of-64 ~ 2.2x waste) to
// EDGE-PARALLEL: one lane = one sorted edge, coalesced edge-word loads,
// in-wave segmented reduction by dst node (shfl scan), segment tails
// atomicAdd float partials (~800k segments, <=8 writers/addr). Tiny
// thread-per-node epilogue passes apply dinv/W1/relu/W2/bias.
//
// localC now emits the full packed word (ld<<18|src) in sorted order so
// agg can recover dst = (dp<<11)|ld; dp via LDS binary search of colStart.
//
// ws: colTotal|colStart|cntmatA[B1*P]|runStart[P*4*2049]|packed[E]|sorted[E]
//     (dinv|g|hs2|acc1|acc2 overlay packed after localC; 13*nd <= E)

#define EPB   8192   // edges per pass-A block
#define PART  2048   // nodes per partition
#define LPBIT 11
#define SRCB  18     // src bits in packed
#define BC    4      // localC sub-blocks per dp
#define RSTR  2049   // runStart stride per (dp,b)
#define STCAP 17408  // LDS stage words (68 KB); max expected ~16.6k

// ---------------- Pass A ----------------

__global__ __launch_bounds__(512) void countA_kernel(
    const int* __restrict__ dst, int* __restrict__ cntmat, int E, int P) {
    __shared__ int cnt[128];
    int tid = threadIdx.x;
    if (tid < 128) cnt[tid] = 0;
    __syncthreads();
    int nv4 = E >> 2;
    int b4 = (blockIdx.x * EPB) >> 2;
    int e4 = min(b4 + (EPB >> 2), nv4);
    const int4* d4 = (const int4*)dst;
    #pragma unroll
    for (int k = 0; k < (EPB >> 2); k += 512) {
        int i = b4 + k + tid;
        if (i < e4) {
            int4 d = d4[i];
            atomicAdd(&cnt[d.x >> LPBIT], 1);
            atomicAdd(&cnt[d.y >> LPBIT], 1);
            atomicAdd(&cnt[d.z >> LPBIT], 1);
            atomicAdd(&cnt[d.w >> LPBIT], 1);
        }
    }
    if (blockIdx.x == gridDim.x - 1) {  // scalar tail (E % 4)
        int e = (nv4 << 2) + tid;
        if (e < E) atomicAdd(&cnt[dst[e] >> LPBIT], 1);
    }
    __syncthreads();
    int* row = cntmat + (size_t)blockIdx.x * P;
    if (tid < P) row[tid] = cnt[tid];
}

__global__ __launch_bounds__(256) void colscanA_kernel(
    int* __restrict__ cntmat, int* __restrict__ colTotal, int B, int P) {
    __shared__ int sdata[256];
    int p = blockIdx.x, tid = threadIdx.x;
    int v[4];
    int s = 0;
    #pragma unroll
    for (int k = 0; k < 4; k++) {
        int b = tid * 4 + k;
        v[k] = (b < B) ? cntmat[(size_t)b * P + p] : 0;
        s += v[k];
    }
    int x = s;
    sdata[tid] = x;
    __syncthreads();
    for (int off = 1; off < 256; off <<= 1) {
        int t = (tid >= off) ? sdata[tid - off] : 0;
        __syncthreads();
        x += t;
        sdata[tid] = x;
        __syncthreads();
    }
    int run = x - s;
    #pragma unroll
    for (int k = 0; k < 4; k++) {
        int b = tid * 4 + k;
        if (b < B) cntmat[(size_t)b * P + p] = run;
        run += v[k];
    }
    if (tid == 255) colTotal[p] = x;
}

__global__ __launch_bounds__(256) void totalscanA_kernel(
    const int* __restrict__ colTotal, int* __restrict__ colStart,
    int P, int E) {
    __shared__ int sdata[256];
    int tid = threadIdx.x;
    int v[4];
    int s = 0;
    #pragma unroll
    for (int k = 0; k < 4; k++) {
        int i = tid * 4 + k;
        v[k] = (i < P) ? colTotal[i] : 0;
        s += v[k];
    }
    int x = s;
    sdata[tid] = x;
    __syncthreads();
    for (int off = 1; off < 256; off <<= 1) {
        int t = (tid >= off) ? sdata[tid - off] : 0;
        __syncthreads();
        x += t;
        sdata[tid] = x;
        __syncthreads();
    }
    int run = x - s;
    #pragma unroll
    for (int k = 0; k < 4; k++) {
        int i = tid * 4 + k;
        if (i < P) colStart[i] = run;
        run += v[k];
    }
    if (tid == 0) colStart[P] = E;
}

__global__ __launch_bounds__(512) void scatterA_kernel(
    const int* __restrict__ src, const int* __restrict__ dst,
    const int* __restrict__ cntmat, const int* __restrict__ colStart,
    unsigned* __restrict__ packed, int E, int P) {
    __shared__ int cur[128];
    int tid = threadIdx.x;
    if (tid < P) cur[tid] = colStart[tid] + cntmat[(size_t)blockIdx.x * P + tid];
    __syncthreads();
    int nv4 = E >> 2;
    int b4 = (blockIdx.x * EPB) >> 2;
    int e4 = min(b4 + (EPB >> 2), nv4);
    const int4* d4 = (const int4*)dst;
    const int4* s4 = (const int4*)src;
    #pragma unroll
    for (int k = 0; k < (EPB >> 2); k += 512) {
        int i = b4 + k + tid;
        if (i < e4) {
            int4 d = d4[i];
            int4 sv = s4[i];
            int p0 = atomicAdd(&cur[d.x >> LPBIT], 1);
            packed[p0] = ((unsigned)(d.x & (PART - 1)) << SRCB) | (unsigned)sv.x;
            int p1 = atomicAdd(&cur[d.y >> LPBIT], 1);
            packed[p1] = ((unsigned)(d.y & (PART - 1)) << SRCB) | (unsigned)sv.y;
            int p2 = atomicAdd(&cur[d.z >> LPBIT], 1);
            packed[p2] = ((unsigned)(d.z & (PART - 1)) << SRCB) | (unsigned)sv.z;
            int p3 = atomicAdd(&cur[d.w >> LPBIT], 1);
            packed[p3] = ((unsigned)(d.w & (PART - 1)) << SRCB) | (unsigned)sv.w;
        }
    }
    if (blockIdx.x == gridDim.x - 1) {  // scalar tail
        int e = (nv4 << 2) + tid;
        if (e < E) {
            int d = dst[e];
            int pos = atomicAdd(&cur[d >> LPBIT], 1);
            packed[pos] = ((unsigned)(d & (PART - 1)) << SRCB) | (unsigned)src[e];
        }
    }
}

// ---------------- localC: in-place LDS counting sort per 16k range --------
// Emits FULL packed words (ld<<18|src) in (ld)-sorted order.

__global__ __launch_bounds__(512) void localC_kernel(
    const unsigned* __restrict__ packed, const int* __restrict__ colStart,
    int* __restrict__ runStart, int* __restrict__ sorted) {
    __shared__ int hist[PART];      // counts -> absolute cursors
    __shared__ int sdata[512];
    __shared__ unsigned stage[STCAP];
    int tid = threadIdx.x;
    int dp = blockIdx.x >> 2, b = blockIdx.x & (BC - 1);
    int s0 = colStart[dp], len = colStart[dp + 1] - s0;
    int lo = s0 + (int)(((long long)len * b) / BC);
    int hi = s0 + (int)(((long long)len * (b + 1)) / BC);
    for (int k = tid; k < PART; k += 512) hist[k] = 0;
    __syncthreads();
    for (int i = lo + tid; i < hi; i += 512)
        atomicAdd(&hist[packed[i] >> SRCB], 1);
    __syncthreads();
    // exclusive scan of hist[2048], 4 elems/thread
    int off = tid * 4;
    int v0 = hist[off], v1 = hist[off + 1], v2 = hist[off + 2], v3 = hist[off + 3];
    int s = v0 + v1 + v2 + v3;
    int x = s;
    sdata[tid] = x;
    __syncthreads();
    for (int o = 1; o < 512; o <<= 1) {
        int t = (tid >= o) ? sdata[tid - o] : 0;
        __syncthreads();
        x += t;
        sdata[tid] = x;
        __syncthreads();
    }
    int run = x - s;  // exclusive prefix of this thread's 4 buckets
    int* rs = runStart + (size_t)(dp * BC + b) * RSTR;
    int c0 = lo + run, c1 = c0 + v0, c2 = c1 + v1, c3 = c2 + v2;
    rs[off] = c0; rs[off + 1] = c1; rs[off + 2] = c2; rs[off + 3] = c3;
    __syncthreads();  // all v-reads done before cursor overwrite
    hist[off] = c0; hist[off + 1] = c1; hist[off + 2] = c2; hist[off + 3] = c3;
    if (tid == 0) rs[PART] = hi;  // end sentinel
    __syncthreads();
    // place into LDS stage (absolute pos - lo), then coalesced flush
    int total = hi - lo;
    bool ovf = total > STCAP;
    for (int i = lo + tid; i < hi; i += 512) {
        unsigned w = packed[i];
        int pos = atomicAdd(&hist[w >> SRCB], 1);
        if (!ovf) stage[pos - lo] = w;
        else sorted[pos] = (int)w;
    }
    __syncthreads();
    if (!ovf)
        for (int j = tid; j < total; j += 512) sorted[lo + j] = (int)stage[j];
}

// ---------------- Node-side ----------------

__global__ __launch_bounds__(512) void dinvg_kernel(
    const int* __restrict__ runStart, const float* __restrict__ x,
    float* __restrict__ dinv, float* __restrict__ g,
    float* __restrict__ acc1, float* __restrict__ acc2, int n) {
    int i = blockIdx.x * 512 + threadIdx.x;
    if (i >= n) return;
    int dp = i >> LPBIT, ld = i & (PART - 1);
    int deg = 0;
    #pragma unroll
    for (int b = 0; b < BC; b++) {
        const int* rs = runStart + (size_t)(dp * BC + b) * RSTR + ld;
        deg += rs[1] - rs[0];
    }
    float d = rsqrtf((float)deg + 1.0f);  // +1 self-loop
    dinv[i] = d;
    float2 xv = ((const float2*)x)[i];
    ((float2*)g)[i] = make_float2(xv.x * d, xv.y * d);
    ((float2*)acc1)[i] = make_float2(0.0f, 0.0f);
    ((float4*)acc2)[i] = make_float4(0.0f, 0.0f, 0.0f, 0.0f);
}

// ---------------- Edge-parallel aggregation ----------------
// lane = one sorted edge; segmented shfl-scan by dst node; tails atomicAdd.

__global__ __launch_bounds__(512) void agg1e_kernel(
    const int* __restrict__ sorted, const int* __restrict__ colStart,
    const float* __restrict__ g, float* __restrict__ acc1, int E, int P) {
    __shared__ int cs[132];
    int tid = threadIdx.x;
    for (int k = tid; k <= P; k += 512) cs[k] = colStart[k];
    __syncthreads();
    int e = blockIdx.x * 512 + tid;
    int lane = tid & 63;
    int sid = -1;
    float s0 = 0.0f, s1 = 0.0f;
    if (e < E) {
        unsigned w = (unsigned)sorted[e];
        int lo = 0, hi = P;
        while (hi - lo > 1) { int mid = (lo + hi) >> 1; if (e >= cs[mid]) lo = mid; else hi = mid; }
        sid = (lo << LPBIT) | (int)(w >> SRCB);
        int src = (int)(w & ((1u << SRCB) - 1));
        float2 gv = ((const float2*)g)[src];
        s0 = gv.x; s1 = gv.y;
    }
    #pragma unroll
    for (int off = 1; off < 64; off <<= 1) {
        int ps = __shfl_up(sid, off);
        float p0 = __shfl_up(s0, off);
        float p1 = __shfl_up(s1, off);
        if (lane >= off && ps == sid) { s0 += p0; s1 += p1; }
    }
    int ns = __shfl_down(sid, 1);
    bool tail = (lane == 63) || (ns != sid);
    if (tail && sid >= 0) {
        atomicAdd(&acc1[2 * (size_t)sid],     s0);
        atomicAdd(&acc1[2 * (size_t)sid + 1], s1);
    }
}

__global__ __launch_bounds__(512) void agg2e_kernel(
    const int* __restrict__ sorted, const int* __restrict__ colStart,
    const float* __restrict__ hs2, float* __restrict__ acc2, int E, int P) {
    __shared__ int cs[132];
    int tid = threadIdx.x;
    for (int k = tid; k <= P; k += 512) cs[k] = colStart[k];
    __syncthreads();
    int e = blockIdx.x * 512 + tid;
    int lane = tid & 63;
    int sid = -1;
    float s0 = 0.0f, s1 = 0.0f, s2 = 0.0f, s3 = 0.0f;
    if (e < E) {
        unsigned w = (unsigned)sorted[e];
        int lo = 0, hi = P;
        while (hi - lo > 1) { int mid = (lo + hi) >> 1; if (e >= cs[mid]) lo = mid; else hi = mid; }
        sid = (lo << LPBIT) | (int)(w >> SRCB);
        int src = (int)(w & ((1u << SRCB) - 1));
        float4 hv = ((const float4*)hs2)[src];
        s0 = hv.x; s1 = hv.y; s2 = hv.z; s3 = hv.w;
    }
    #pragma unroll
    for (int off = 1; off < 64; off <<= 1) {
        int ps = __shfl_up(sid, off);
        float p0 = __shfl_up(s0, off);
        float p1 = __shfl_up(s1, off);
        float p2 = __shfl_up(s2, off);
        float p3 = __shfl_up(s3, off);
        if (lane >= off && ps == sid) { s0 += p0; s1 += p1; s2 += p2; s3 += p3; }
    }
    int ns = __shfl_down(sid, 1);
    bool tail = (lane == 63) || (ns != sid);
    if (tail && sid >= 0) {
        atomicAdd(&acc2[4 * (size_t)sid],     s0);
        atomicAdd(&acc2[4 * (size_t)sid + 1], s1);
        atomicAdd(&acc2[4 * (size_t)sid + 2], s2);
        atomicAdd(&acc2[4 * (size_t)sid + 3], s3);
    }
}

// ---------------- Node epilogues ----------------

__global__ __launch_bounds__(512) void node1_kernel(
    const float* __restrict__ acc1, const float* __restrict__ g,
    const float* __restrict__ dinv, const float* __restrict__ W1,
    const float* __restrict__ b1, const float* __restrict__ W2,
    float* __restrict__ hs2, int n) {
    int i = blockIdx.x * 512 + threadIdx.x;
    if (i >= n) return;
    float d = dinv[i];
    float2 a = ((const float2*)acc1)[i];
    float2 gi = ((const float2*)g)[i];
    float s0 = (a.x + gi.x) * d;
    float s1 = (a.y + gi.y) * d;
    float oc0 = 0.0f, oc1 = 0.0f, oc2 = 0.0f, oc3 = 0.0f;
    #pragma unroll
    for (int f = 0; f < 8; f++) {
        float h = fmaxf(s0 * W1[f] + s1 * W1[8 + f] + b1[f], 0.0f);
        oc0 += h * W2[4 * f];
        oc1 += h * W2[4 * f + 1];
        oc2 += h * W2[4 * f + 2];
        oc3 += h * W2[4 * f + 3];
    }
    float4 o;
    o.x = oc0 * d; o.y = oc1 * d; o.z = oc2 * d; o.w = oc3 * d;
    ((float4*)hs2)[i] = o;
}

__global__ __launch_bounds__(512) void node2_kernel(
    const float* __restrict__ acc2, const float* __restrict__ hs2,
    const float* __restrict__ dinv, const float* __restrict__ b2,
    float* __restrict__ out, int n) {
    int i = blockIdx.x * 512 + threadIdx.x;
    if (i >= n) return;
    float d = dinv[i];
    float4 a = ((const float4*)acc2)[i];
    float4 hv = ((const float4*)hs2)[i];
    float4 o;
    o.x = d * (a.x + hv.x) + b2[0];
    o.y = d * (a.y + hv.y) + b2[1];
    o.z = d * (a.z + hv.z) + b2[2];
    o.w = d * (a.w + hv.w) + b2[3];
    ((float4*)out)[i] = o;
}

extern "C" void kernel_launch(void* const* d_in, const int* in_sizes, int n_in,
                              void* d_out, int out_size, void* d_ws, size_t ws_size,
                              hipStream_t stream) {
    const float* x   = (const float*)d_in[0];
    const int*   ei  = (const int*)d_in[1];
    const float* W1  = (const float*)d_in[2];
    const float* b1  = (const float*)d_in[3];
    const float* W2  = (const float*)d_in[4];
    const float* b2  = (const float*)d_in[5];
    float* out = (float*)d_out;

    const int n = in_sizes[0] / 2;  // x is [N,2]
    const int E = in_sizes[1] / 2;  // edge_index is [2,E]
    const int* src = ei;
    const int* dst = ei + E;

    const int P  = (n + PART - 1) >> LPBIT;  // 98
    const int B1 = (E + EPB - 1) / EPB;      // 782

    int* ws = (int*)d_ws;
    int* colTotal = ws;                                      // 1024
    int* colStart = ws + 1024;                               // 1024
    int* cntmatA  = ws + 2048;                               // B1*P
    size_t cmsz = (((size_t)B1 * P) + 3) & ~(size_t)3;
    int* runStart = cntmatA + cmsz;                          // P*BC*RSTR
    size_t rssz = (((size_t)P * BC * RSTR) + 3) & ~(size_t)3;
    unsigned* packed = (unsigned*)(runStart + rssz);         // E
    int* sorted = (int*)(packed + E);                        // E
    // packed region is dead after localC; overlay node buffers (13*nd <= E):
    size_t nd = (size_t)P << LPBIT;                          // 200704
    float* dinv = (float*)packed;                            // nd
    float* g    = dinv + nd;                                 // 2*nd
    float* hs2  = g + 2 * nd;                                // 4*nd
    float* acc1 = hs2 + 4 * nd;                              // 2*nd
    float* acc2 = acc1 + 2 * nd;                             // 4*nd

    const int gN = (n + 511) / 512;
    const int gE = (E + 511) / 512;

    countA_kernel    <<<B1, 512, 0, stream>>>(dst, cntmatA, E, P);
    colscanA_kernel  <<<P, 256, 0, stream>>>(cntmatA, colTotal, B1, P);
    totalscanA_kernel<<<1, 256, 0, stream>>>(colTotal, colStart, P, E);
    scatterA_kernel  <<<B1, 512, 0, stream>>>(src, dst, cntmatA, colStart, packed, E, P);
    localC_kernel    <<<P * BC, 512, 0, stream>>>(packed, colStart, runStart, sorted);
    dinvg_kernel     <<<gN, 512, 0, stream>>>(runStart, x, dinv, g, acc1, acc2, n);
    agg1e_kernel     <<<gE, 512, 0, stream>>>(sorted, colStart, g, acc1, E, P);
    node1_kernel     <<<gN, 512, 0, stream>>>(acc1, g, dinv, W1, b1, W2, hs2, n);
    agg2e_kernel     <<<gE, 512, 0, stream>>>(sorted, colStart, hs2, acc2, E, P);
    node2_kernel     <<<gN, 512, 0, stream>>>(acc2, hs2, dinv, b2, out, n);
}

// Round 3
// 272.137 us; speedup vs baseline: 1.0712x; 1.0712x over previous
//
#include <hip/hip_runtime.h>

// GCN 2-layer on MI355X — Round 13: sort pipeline unchanged. Aggregation:
// node-aligned edge-parallel blocks. Block owns 128 nodes = 4 contiguous
// spans of sorted[] (via runStart CSR): coalesced edge-word reads, gather,
// wave segmented shfl-scan by local node id, tails atomicAdd into a 2KB
// LDS accumulator (ds_add_f32, ~8 distinct-addr tails/wave), then fused
// per-node epilogue with NON-atomic stores (one writer per node).
// Removes R12's global FP atomics (61.7MB write-drain regression) and the
// acc buffers + node1/node2 passes entirely.
//
// g[j] = x[j]*dinv[j].  layer1: hs2 via relu(dinv*(sum g)+b1)@W2*dinv
// layer2: out[i] = dinv[i]*(sum hs2[src]+hs2[i]) + b2
//
// ws: colTotal|colStart|cntmatA[B1*P]|runStart[P*4*2049]|packed[E]|sorted[E]
//     (dinv|g|hs2 overlay packed after localC; 7*nd <= E)

#define EPB   8192   // edges per pass-A block
#define PART  2048   // nodes per partition
#define LPBIT 11
#define SRCB  18     // src bits in packed
#define BC    4      // localC sub-blocks per dp
#define RSTR  2049   // runStart stride per (dp,b)
#define STCAP 17408  // LDS stage words (68 KB); max expected ~16.6k
#define NB    128    // nodes per aggregation block

// ---------------- Pass A ----------------

__global__ __launch_bounds__(512) void countA_kernel(
    const int* __restrict__ dst, int* __restrict__ cntmat, int E, int P) {
    __shared__ int cnt[128];
    int tid = threadIdx.x;
    if (tid < 128) cnt[tid] = 0;
    __syncthreads();
    int nv4 = E >> 2;
    int b4 = (blockIdx.x * EPB) >> 2;
    int e4 = min(b4 + (EPB >> 2), nv4);
    const int4* d4 = (const int4*)dst;
    #pragma unroll
    for (int k = 0; k < (EPB >> 2); k += 512) {
        int i = b4 + k + tid;
        if (i < e4) {
            int4 d = d4[i];
            atomicAdd(&cnt[d.x >> LPBIT], 1);
            atomicAdd(&cnt[d.y >> LPBIT], 1);
            atomicAdd(&cnt[d.z >> LPBIT], 1);
            atomicAdd(&cnt[d.w >> LPBIT], 1);
        }
    }
    if (blockIdx.x == gridDim.x - 1) {  // scalar tail (E % 4)
        int e = (nv4 << 2) + tid;
        if (e < E) atomicAdd(&cnt[dst[e] >> LPBIT], 1);
    }
    __syncthreads();
    int* row = cntmat + (size_t)blockIdx.x * P;
    if (tid < P) row[tid] = cnt[tid];
}

__global__ __launch_bounds__(256) void colscanA_kernel(
    int* __restrict__ cntmat, int* __restrict__ colTotal, int B, int P) {
    __shared__ int sdata[256];
    int p = blockIdx.x, tid = threadIdx.x;
    int v[4];
    int s = 0;
    #pragma unroll
    for (int k = 0; k < 4; k++) {
        int b = tid * 4 + k;
        v[k] = (b < B) ? cntmat[(size_t)b * P + p] : 0;
        s += v[k];
    }
    int x = s;
    sdata[tid] = x;
    __syncthreads();
    for (int off = 1; off < 256; off <<= 1) {
        int t = (tid >= off) ? sdata[tid - off] : 0;
        __syncthreads();
        x += t;
        sdata[tid] = x;
        __syncthreads();
    }
    int run = x - s;
    #pragma unroll
    for (int k = 0; k < 4; k++) {
        int b = tid * 4 + k;
        if (b < B) cntmat[(size_t)b * P + p] = run;
        run += v[k];
    }
    if (tid == 255) colTotal[p] = x;
}

__global__ __launch_bounds__(256) void totalscanA_kernel(
    const int* __restrict__ colTotal, int* __restrict__ colStart,
    int P, int E) {
    __shared__ int sdata[256];
    int tid = threadIdx.x;
    int v[4];
    int s = 0;
    #pragma unroll
    for (int k = 0; k < 4; k++) {
        int i = tid * 4 + k;
        v[k] = (i < P) ? colTotal[i] : 0;
        s += v[k];
    }
    int x = s;
    sdata[tid] = x;
    __syncthreads();
    for (int off = 1; off < 256; off <<= 1) {
        int t = (tid >= off) ? sdata[tid - off] : 0;
        __syncthreads();
        x += t;
        sdata[tid] = x;
        __syncthreads();
    }
    int run = x - s;
    #pragma unroll
    for (int k = 0; k < 4; k++) {
        int i = tid * 4 + k;
        if (i < P) colStart[i] = run;
        run += v[k];
    }
    if (tid == 0) colStart[P] = E;
}

__global__ __launch_bounds__(512) void scatterA_kernel(
    const int* __restrict__ src, const int* __restrict__ dst,
    const int* __restrict__ cntmat, const int* __restrict__ colStart,
    unsigned* __restrict__ packed, int E, int P) {
    __shared__ int cur[128];
    int tid = threadIdx.x;
    if (tid < P) cur[tid] = colStart[tid] + cntmat[(size_t)blockIdx.x * P + tid];
    __syncthreads();
    int nv4 = E >> 2;
    int b4 = (blockIdx.x * EPB) >> 2;
    int e4 = min(b4 + (EPB >> 2), nv4);
    const int4* d4 = (const int4*)dst;
    const int4* s4 = (const int4*)src;
    #pragma unroll
    for (int k = 0; k < (EPB >> 2); k += 512) {
        int i = b4 + k + tid;
        if (i < e4) {
            int4 d = d4[i];
            int4 sv = s4[i];
            int p0 = atomicAdd(&cur[d.x >> LPBIT], 1);
            packed[p0] = ((unsigned)(d.x & (PART - 1)) << SRCB) | (unsigned)sv.x;
            int p1 = atomicAdd(&cur[d.y >> LPBIT], 1);
            packed[p1] = ((unsigned)(d.y & (PART - 1)) << SRCB) | (unsigned)sv.y;
            int p2 = atomicAdd(&cur[d.z >> LPBIT], 1);
            packed[p2] = ((unsigned)(d.z & (PART - 1)) << SRCB) | (unsigned)sv.z;
            int p3 = atomicAdd(&cur[d.w >> LPBIT], 1);
            packed[p3] = ((unsigned)(d.w & (PART - 1)) << SRCB) | (unsigned)sv.w;
        }
    }
    if (blockIdx.x == gridDim.x - 1) {  // scalar tail
        int e = (nv4 << 2) + tid;
        if (e < E) {
            int d = dst[e];
            int pos = atomicAdd(&cur[d >> LPBIT], 1);
            packed[pos] = ((unsigned)(d & (PART - 1)) << SRCB) | (unsigned)src[e];
        }
    }
}

// ---------------- localC: in-place LDS counting sort per 16k range --------
// Emits FULL packed words (ld<<18|src) in (ld)-sorted order.

__global__ __launch_bounds__(512) void localC_kernel(
    const unsigned* __restrict__ packed, const int* __restrict__ colStart,
    int* __restrict__ runStart, int* __restrict__ sorted) {
    __shared__ int hist[PART];      // counts -> absolute cursors
    __shared__ int sdata[512];
    __shared__ unsigned stage[STCAP];
    int tid = threadIdx.x;
    int dp = blockIdx.x >> 2, b = blockIdx.x & (BC - 1);
    int s0 = colStart[dp], len = colStart[dp + 1] - s0;
    int lo = s0 + (int)(((long long)len * b) / BC);
    int hi = s0 + (int)(((long long)len * (b + 1)) / BC);
    for (int k = tid; k < PART; k += 512) hist[k] = 0;
    __syncthreads();
    for (int i = lo + tid; i < hi; i += 512)
        atomicAdd(&hist[packed[i] >> SRCB], 1);
    __syncthreads();
    // exclusive scan of hist[2048], 4 elems/thread
    int off = tid * 4;
    int v0 = hist[off], v1 = hist[off + 1], v2 = hist[off + 2], v3 = hist[off + 3];
    int s = v0 + v1 + v2 + v3;
    int x = s;
    sdata[tid] = x;
    __syncthreads();
    for (int o = 1; o < 512; o <<= 1) {
        int t = (tid >= o) ? sdata[tid - o] : 0;
        __syncthreads();
        x += t;
        sdata[tid] = x;
        __syncthreads();
    }
    int run = x - s;  // exclusive prefix of this thread's 4 buckets
    int* rs = runStart + (size_t)(dp * BC + b) * RSTR;
    int c0 = lo + run, c1 = c0 + v0, c2 = c1 + v1, c3 = c2 + v2;
    rs[off] = c0; rs[off + 1] = c1; rs[off + 2] = c2; rs[off + 3] = c3;
    __syncthreads();  // all v-reads done before cursor overwrite
    hist[off] = c0; hist[off + 1] = c1; hist[off + 2] = c2; hist[off + 3] = c3;
    if (tid == 0) rs[PART] = hi;  // end sentinel
    __syncthreads();
    // place into LDS stage (absolute pos - lo), then coalesced flush
    int total = hi - lo;
    bool ovf = total > STCAP;
    for (int i = lo + tid; i < hi; i += 512) {
        unsigned w = packed[i];
        int pos = atomicAdd(&hist[w >> SRCB], 1);
        if (!ovf) stage[pos - lo] = w;
        else sorted[pos] = (int)w;
    }
    __syncthreads();
    if (!ovf)
        for (int j = tid; j < total; j += 512) sorted[lo + j] = (int)stage[j];
}

// ---------------- Node-side ----------------

__global__ __launch_bounds__(512) void dinvg_kernel(
    const int* __restrict__ runStart, const float* __restrict__ x,
    float* __restrict__ dinv, float* __restrict__ g, int n) {
    int i = blockIdx.x * 512 + threadIdx.x;
    if (i >= n) return;
    int dp = i >> LPBIT, ld = i & (PART - 1);
    int deg = 0;
    #pragma unroll
    for (int b = 0; b < BC; b++) {
        const int* rs = runStart + (size_t)(dp * BC + b) * RSTR + ld;
        deg += rs[1] - rs[0];
    }
    float d = rsqrtf((float)deg + 1.0f);  // +1 self-loop
    dinv[i] = d;
    float2 xv = ((const float2*)x)[i];
    ((float2*)g)[i] = make_float2(xv.x * d, xv.y * d);
}

// ---------------- Fused node-aligned edge-parallel aggregation -----------
// Block owns nodes [i0, i0+NB). For each bucket b, edges of these nodes are
// the contiguous span [rs[l0], rs[l0+NB]) of sorted[]. Coalesced edge reads,
// segmented shfl-scan by local node id, tails -> LDS atomicAdd. Then fused
// epilogue, one writer per node, plain stores.

__global__ __launch_bounds__(512) void agg1f_kernel(
    const int* __restrict__ sorted, const int* __restrict__ runStart,
    const float* __restrict__ g, const float* __restrict__ dinv,
    const float* __restrict__ W1, const float* __restrict__ b1,
    const float* __restrict__ W2, float* __restrict__ hs2, int n) {
    __shared__ float acc[NB * 2];
    int tid = threadIdx.x;
    int i0 = blockIdx.x * NB;
    int dp = i0 >> LPBIT, l0 = i0 & (PART - 1);
    for (int k = tid; k < NB * 2; k += 512) acc[k] = 0.0f;
    __syncthreads();
    int lane = tid & 63;
    #pragma unroll
    for (int b = 0; b < BC; b++) {
        const int* rs = runStart + (size_t)(dp * BC + b) * RSTR;
        int lo = rs[l0], hi = rs[l0 + NB];
        for (int base = lo; base < hi; base += 512) {
            int e = base + tid;
            int sid = -1;
            float s0 = 0.0f, s1 = 0.0f;
            if (e < hi) {
                unsigned w = (unsigned)sorted[e];
                sid = (int)(w >> SRCB) - l0;
                int src = (int)(w & ((1u << SRCB) - 1));
                float2 gv = ((const float2*)g)[src];
                s0 = gv.x; s1 = gv.y;
            }
            #pragma unroll
            for (int off = 1; off < 64; off <<= 1) {
                int ps = __shfl_up(sid, off);
                float p0 = __shfl_up(s0, off);
                float p1 = __shfl_up(s1, off);
                if (lane >= off && ps == sid) { s0 += p0; s1 += p1; }
            }
            int ns = __shfl_down(sid, 1);
            bool tail = (lane == 63) || (ns != sid);
            if (tail && sid >= 0) {
                atomicAdd(&acc[sid * 2],     s0);
                atomicAdd(&acc[sid * 2 + 1], s1);
            }
        }
    }
    __syncthreads();
    if (tid < NB) {
        int i = i0 + tid;
        if (i < n) {
            float d = dinv[i];
            float2 gi = ((const float2*)g)[i];
            float s0 = (acc[tid * 2]     + gi.x) * d;
            float s1 = (acc[tid * 2 + 1] + gi.y) * d;
            float oc0 = 0.0f, oc1 = 0.0f, oc2 = 0.0f, oc3 = 0.0f;
            #pragma unroll
            for (int f = 0; f < 8; f++) {
                float h = fmaxf(s0 * W1[f] + s1 * W1[8 + f] + b1[f], 0.0f);
                oc0 += h * W2[4 * f];
                oc1 += h * W2[4 * f + 1];
                oc2 += h * W2[4 * f + 2];
                oc3 += h * W2[4 * f + 3];
            }
            float4 o;
            o.x = oc0 * d; o.y = oc1 * d; o.z = oc2 * d; o.w = oc3 * d;
            ((float4*)hs2)[i] = o;
        }
    }
}

__global__ __launch_bounds__(512) void agg2f_kernel(
    const int* __restrict__ sorted, const int* __restrict__ runStart,
    const float* __restrict__ hs2, const float* __restrict__ dinv,
    const float* __restrict__ b2, float* __restrict__ out, int n) {
    __shared__ float acc[NB * 4];
    int tid = threadIdx.x;
    int i0 = blockIdx.x * NB;
    int dp = i0 >> LPBIT, l0 = i0 & (PART - 1);
    for (int k = tid; k < NB * 4; k += 512) acc[k] = 0.0f;
    __syncthreads();
    int lane = tid & 63;
    #pragma unroll
    for (int b = 0; b < BC; b++) {
        const int* rs = runStart + (size_t)(dp * BC + b) * RSTR;
        int lo = rs[l0], hi = rs[l0 + NB];
        for (int base = lo; base < hi; base += 512) {
            int e = base + tid;
            int sid = -1;
            float s0 = 0.0f, s1 = 0.0f, s2 = 0.0f, s3 = 0.0f;
            if (e < hi) {
                unsigned w = (unsigned)sorted[e];
                sid = (int)(w >> SRCB) - l0;
                int src = (int)(w & ((1u << SRCB) - 1));
                float4 hv = ((const float4*)hs2)[src];
                s0 = hv.x; s1 = hv.y; s2 = hv.z; s3 = hv.w;
            }
            #pragma unroll
            for (int off = 1; off < 64; off <<= 1) {
                int ps = __shfl_up(sid, off);
                float p0 = __shfl_up(s0, off);
                float p1 = __shfl_up(s1, off);
                float p2 = __shfl_up(s2, off);
                float p3 = __shfl_up(s3, off);
                if (lane >= off && ps == sid) { s0 += p0; s1 += p1; s2 += p2; s3 += p3; }
            }
            int ns = __shfl_down(sid, 1);
            bool tail = (lane == 63) || (ns != sid);
            if (tail && sid >= 0) {
                atomicAdd(&acc[sid * 4],     s0);
                atomicAdd(&acc[sid * 4 + 1], s1);
                atomicAdd(&acc[sid * 4 + 2], s2);
                atomicAdd(&acc[sid * 4 + 3], s3);
            }
        }
    }
    __syncthreads();
    if (tid < NB) {
        int i = i0 + tid;
        if (i < n) {
            float d = dinv[i];
            float4 hv = ((const float4*)hs2)[i];
            float4 o;
            o.x = d * (acc[tid * 4]     + hv.x) + b2[0];
            o.y = d * (acc[tid * 4 + 1] + hv.y) + b2[1];
            o.z = d * (acc[tid * 4 + 2] + hv.z) + b2[2];
            o.w = d * (acc[tid * 4 + 3] + hv.w) + b2[3];
            ((float4*)out)[i] = o;
        }
    }
}

extern "C" void kernel_launch(void* const* d_in, const int* in_sizes, int n_in,
                              void* d_out, int out_size, void* d_ws, size_t ws_size,
                              hipStream_t stream) {
    const float* x   = (const float*)d_in[0];
    const int*   ei  = (const int*)d_in[1];
    const float* W1  = (const float*)d_in[2];
    const float* b1  = (const float*)d_in[3];
    const float* W2  = (const float*)d_in[4];
    const float* b2  = (const float*)d_in[5];
    float* out = (float*)d_out;

    const int n = in_sizes[0] / 2;  // x is [N,2]
    const int E = in_sizes[1] / 2;  // edge_index is [2,E]
    const int* src = ei;
    const int* dst = ei + E;

    const int P  = (n + PART - 1) >> LPBIT;  // 98
    const int B1 = (E + EPB - 1) / EPB;      // 782

    int* ws = (int*)d_ws;
    int* colTotal = ws;                                      // 1024
    int* colStart = ws + 1024;                               // 1024
    int* cntmatA  = ws + 2048;                               // B1*P
    size_t cmsz = (((size_t)B1 * P) + 3) & ~(size_t)3;
    int* runStart = cntmatA + cmsz;                          // P*BC*RSTR
    size_t rssz = (((size_t)P * BC * RSTR) + 3) & ~(size_t)3;
    unsigned* packed = (unsigned*)(runStart + rssz);         // E
    int* sorted = (int*)(packed + E);                        // E
    // packed region is dead after localC; overlay node buffers (7*nd <= E):
    size_t nd = (size_t)P << LPBIT;                          // 200704
    float* dinv = (float*)packed;                            // nd
    float* g    = dinv + nd;                                 // 2*nd
    float* hs2  = g + 2 * nd;                                // 4*nd

    const int gN = (n + 511) / 512;
    const int gB = (n + NB - 1) / NB;

    countA_kernel    <<<B1, 512, 0, stream>>>(dst, cntmatA, E, P);
    colscanA_kernel  <<<P, 256, 0, stream>>>(cntmatA, colTotal, B1, P);
    totalscanA_kernel<<<1, 256, 0, stream>>>(colTotal, colStart, P, E);
    scatterA_kernel  <<<B1, 512, 0, stream>>>(src, dst, cntmatA, colStart, packed, E, P);
    localC_kernel    <<<P * BC, 512, 0, stream>>>(packed, colStart, runStart, sorted);
    dinvg_kernel     <<<gN, 512, 0, stream>>>(runStart, x, dinv, g, n);
    agg1f_kernel     <<<gB, 512, 0, stream>>>(sorted, runStart, g, dinv, W1, b1, W2, hs2, n);
    agg2f_kernel     <<<gB, 512, 0, stream>>>(sorted, runStart, hs2, dinv, b2, out, n);
}

// Round 4
// 245.170 us; speedup vs baseline: 1.1890x; 1.1100x over previous
//
#include <hip/hip_runtime.h>

// GCN 2-layer on MI355X — Round 14: sort pipeline unchanged. Aggregation:
// two-phase LDS-staged, shuffle-free (R13's segmented shfl-scan was
// ~0.5 dependent ds_bpermute per edge -> LDS-pipe bound at 74us).
//   Phase 1 (balanced): 512 threads stride the block's contiguous sorted[]
//     spans: coalesced edge-word read -> random L2 gather -> coalesced LDS
//     stage write. This carries the unavoidable cost (6.4M x 64B L2 lines).
//   Phase 2 (cheap): thread=(node,comp) sums its node's stage entries via
//     scalar ds_read (~32 x 2-4cy); straggler waste only on LDS reads.
// No atomics, no shuffles. agg2 epilogue per-comp (coalesced scalar IO);
// agg1 combines s0/s1 through a small LDS buffer, per-node epilogue.
//
// g[j] = x[j]*dinv[j].  layer1: hs2 via relu(dinv*(sum g)+b1)@W2*dinv
// layer2: out[i] = dinv[i]*(sum hs2[src]+hs2[i]) + b2
//
// ws: colTotal|colStart|cntmatA[B1*P]|runStart[P*4*2049]|packed[E]|sorted[E]
//     (dinv|g|hs2 overlay packed after localC; 7*nd <= E)

#define EPB   8192   // edges per pass-A block
#define PART  2048   // nodes per partition
#define LPBIT 11
#define SRCB  18     // src bits in packed
#define BC    4      // localC sub-blocks per dp
#define RSTR  2049   // runStart stride per (dp,b)
#define STCAP 17408  // LDS stage words (68 KB); max expected ~16.6k
#define NB    128    // nodes per aggregation block
#define CAP   1536   // staged edges per bucket-span (max expected ~1170)

// ---------------- Pass A ----------------

__global__ __launch_bounds__(512) void countA_kernel(
    const int* __restrict__ dst, int* __restrict__ cntmat, int E, int P) {
    __shared__ int cnt[128];
    int tid = threadIdx.x;
    if (tid < 128) cnt[tid] = 0;
    __syncthreads();
    int nv4 = E >> 2;
    int b4 = (blockIdx.x * EPB) >> 2;
    int e4 = min(b4 + (EPB >> 2), nv4);
    const int4* d4 = (const int4*)dst;
    #pragma unroll
    for (int k = 0; k < (EPB >> 2); k += 512) {
        int i = b4 + k + tid;
        if (i < e4) {
            int4 d = d4[i];
            atomicAdd(&cnt[d.x >> LPBIT], 1);
            atomicAdd(&cnt[d.y >> LPBIT], 1);
            atomicAdd(&cnt[d.z >> LPBIT], 1);
            atomicAdd(&cnt[d.w >> LPBIT], 1);
        }
    }
    if (blockIdx.x == gridDim.x - 1) {  // scalar tail (E % 4)
        int e = (nv4 << 2) + tid;
        if (e < E) atomicAdd(&cnt[dst[e] >> LPBIT], 1);
    }
    __syncthreads();
    int* row = cntmat + (size_t)blockIdx.x * P;
    if (tid < P) row[tid] = cnt[tid];
}

__global__ __launch_bounds__(256) void colscanA_kernel(
    int* __restrict__ cntmat, int* __restrict__ colTotal, int B, int P) {
    __shared__ int sdata[256];
    int p = blockIdx.x, tid = threadIdx.x;
    int v[4];
    int s = 0;
    #pragma unroll
    for (int k = 0; k < 4; k++) {
        int b = tid * 4 + k;
        v[k] = (b < B) ? cntmat[(size_t)b * P + p] : 0;
        s += v[k];
    }
    int x = s;
    sdata[tid] = x;
    __syncthreads();
    for (int off = 1; off < 256; off <<= 1) {
        int t = (tid >= off) ? sdata[tid - off] : 0;
        __syncthreads();
        x += t;
        sdata[tid] = x;
        __syncthreads();
    }
    int run = x - s;
    #pragma unroll
    for (int k = 0; k < 4; k++) {
        int b = tid * 4 + k;
        if (b < B) cntmat[(size_t)b * P + p] = run;
        run += v[k];
    }
    if (tid == 255) colTotal[p] = x;
}

__global__ __launch_bounds__(256) void totalscanA_kernel(
    const int* __restrict__ colTotal, int* __restrict__ colStart,
    int P, int E) {
    __shared__ int sdata[256];
    int tid = threadIdx.x;
    int v[4];
    int s = 0;
    #pragma unroll
    for (int k = 0; k < 4; k++) {
        int i = tid * 4 + k;
        v[k] = (i < P) ? colTotal[i] : 0;
        s += v[k];
    }
    int x = s;
    sdata[tid] = x;
    __syncthreads();
    for (int off = 1; off < 256; off <<= 1) {
        int t = (tid >= off) ? sdata[tid - off] : 0;
        __syncthreads();
        x += t;
        sdata[tid] = x;
        __syncthreads();
    }
    int run = x - s;
    #pragma unroll
    for (int k = 0; k < 4; k++) {
        int i = tid * 4 + k;
        if (i < P) colStart[i] = run;
        run += v[k];
    }
    if (tid == 0) colStart[P] = E;
}

__global__ __launch_bounds__(512) void scatterA_kernel(
    const int* __restrict__ src, const int* __restrict__ dst,
    const int* __restrict__ cntmat, const int* __restrict__ colStart,
    unsigned* __restrict__ packed, int E, int P) {
    __shared__ int cur[128];
    int tid = threadIdx.x;
    if (tid < P) cur[tid] = colStart[tid] + cntmat[(size_t)blockIdx.x * P + tid];
    __syncthreads();
    int nv4 = E >> 2;
    int b4 = (blockIdx.x * EPB) >> 2;
    int e4 = min(b4 + (EPB >> 2), nv4);
    const int4* d4 = (const int4*)dst;
    const int4* s4 = (const int4*)src;
    #pragma unroll
    for (int k = 0; k < (EPB >> 2); k += 512) {
        int i = b4 + k + tid;
        if (i < e4) {
            int4 d = d4[i];
            int4 sv = s4[i];
            int p0 = atomicAdd(&cur[d.x >> LPBIT], 1);
            packed[p0] = ((unsigned)(d.x & (PART - 1)) << SRCB) | (unsigned)sv.x;
            int p1 = atomicAdd(&cur[d.y >> LPBIT], 1);
            packed[p1] = ((unsigned)(d.y & (PART - 1)) << SRCB) | (unsigned)sv.y;
            int p2 = atomicAdd(&cur[d.z >> LPBIT], 1);
            packed[p2] = ((unsigned)(d.z & (PART - 1)) << SRCB) | (unsigned)sv.z;
            int p3 = atomicAdd(&cur[d.w >> LPBIT], 1);
            packed[p3] = ((unsigned)(d.w & (PART - 1)) << SRCB) | (unsigned)sv.w;
        }
    }
    if (blockIdx.x == gridDim.x - 1) {  // scalar tail
        int e = (nv4 << 2) + tid;
        if (e < E) {
            int d = dst[e];
            int pos = atomicAdd(&cur[d >> LPBIT], 1);
            packed[pos] = ((unsigned)(d & (PART - 1)) << SRCB) | (unsigned)src[e];
        }
    }
}

// ---------------- localC: in-place LDS counting sort per 16k range --------
// Emits FULL packed words (ld<<18|src) in (ld)-sorted order.

__global__ __launch_bounds__(512) void localC_kernel(
    const unsigned* __restrict__ packed, const int* __restrict__ colStart,
    int* __restrict__ runStart, int* __restrict__ sorted) {
    __shared__ int hist[PART];      // counts -> absolute cursors
    __shared__ int sdata[512];
    __shared__ unsigned stage[STCAP];
    int tid = threadIdx.x;
    int dp = blockIdx.x >> 2, b = blockIdx.x & (BC - 1);
    int s0 = colStart[dp], len = colStart[dp + 1] - s0;
    int lo = s0 + (int)(((long long)len * b) / BC);
    int hi = s0 + (int)(((long long)len * (b + 1)) / BC);
    for (int k = tid; k < PART; k += 512) hist[k] = 0;
    __syncthreads();
    for (int i = lo + tid; i < hi; i += 512)
        atomicAdd(&hist[packed[i] >> SRCB], 1);
    __syncthreads();
    // exclusive scan of hist[2048], 4 elems/thread
    int off = tid * 4;
    int v0 = hist[off], v1 = hist[off + 1], v2 = hist[off + 2], v3 = hist[off + 3];
    int s = v0 + v1 + v2 + v3;
    int x = s;
    sdata[tid] = x;
    __syncthreads();
    for (int o = 1; o < 512; o <<= 1) {
        int t = (tid >= o) ? sdata[tid - o] : 0;
        __syncthreads();
        x += t;
        sdata[tid] = x;
        __syncthreads();
    }
    int run = x - s;  // exclusive prefix of this thread's 4 buckets
    int* rs = runStart + (size_t)(dp * BC + b) * RSTR;
    int c0 = lo + run, c1 = c0 + v0, c2 = c1 + v1, c3 = c2 + v2;
    rs[off] = c0; rs[off + 1] = c1; rs[off + 2] = c2; rs[off + 3] = c3;
    __syncthreads();  // all v-reads done before cursor overwrite
    hist[off] = c0; hist[off + 1] = c1; hist[off + 2] = c2; hist[off + 3] = c3;
    if (tid == 0) rs[PART] = hi;  // end sentinel
    __syncthreads();
    // place into LDS stage (absolute pos - lo), then coalesced flush
    int total = hi - lo;
    bool ovf = total > STCAP;
    for (int i = lo + tid; i < hi; i += 512) {
        unsigned w = packed[i];
        int pos = atomicAdd(&hist[w >> SRCB], 1);
        if (!ovf) stage[pos - lo] = w;
        else sorted[pos] = (int)w;
    }
    __syncthreads();
    if (!ovf)
        for (int j = tid; j < total; j += 512) sorted[lo + j] = (int)stage[j];
}

// ---------------- Node-side ----------------

__global__ __launch_bounds__(512) void dinvg_kernel(
    const int* __restrict__ runStart, const float* __restrict__ x,
    float* __restrict__ dinv, float* __restrict__ g, int n) {
    int i = blockIdx.x * 512 + threadIdx.x;
    if (i >= n) return;
    int dp = i >> LPBIT, ld = i & (PART - 1);
    int deg = 0;
    #pragma unroll
    for (int b = 0; b < BC; b++) {
        const int* rs = runStart + (size_t)(dp * BC + b) * RSTR + ld;
        deg += rs[1] - rs[0];
    }
    float d = rsqrtf((float)deg + 1.0f);  // +1 self-loop
    dinv[i] = d;
    float2 xv = ((const float2*)x)[i];
    ((float2*)g)[i] = make_float2(xv.x * d, xv.y * d);
}

// ---------------- Two-phase LDS-staged aggregation ----------------

__global__ __launch_bounds__(512) void agg1s_kernel(
    const int* __restrict__ sorted, const int* __restrict__ runStart,
    const float* __restrict__ g, const float* __restrict__ dinv,
    const float* __restrict__ W1, const float* __restrict__ b1,
    const float* __restrict__ W2, float* __restrict__ hs2, int n) {
    __shared__ float2 stage2[CAP];
    __shared__ int sb[BC][NB + 1];
    __shared__ float sres[NB * 2];
    float* stage = (float*)stage2;
    int tid = threadIdx.x;
    int i0 = blockIdx.x * NB;
    int dp = i0 >> LPBIT, l0 = i0 & (PART - 1);
    for (int k = tid; k < BC * (NB + 1); k += 512) {
        int b = k / (NB + 1), idx = k - b * (NB + 1);
        sb[b][idx] = runStart[(size_t)(dp * BC + b) * RSTR + l0 + idx];
    }
    int nid = tid >> 2;          // node within block
    int c = tid & 1;             // component
    int half = (tid >> 1) & 1;   // position-half
    float acc = 0.0f;
    __syncthreads();
    #pragma unroll
    for (int b = 0; b < BC; b++) {
        int lo = sb[b][0], hi = sb[b][NB];
        for (int e = lo + tid; e < hi; e += 512) {
            int off = e - lo;
            if (off < CAP) {
                unsigned w = (unsigned)sorted[e];
                int src = (int)(w & ((1u << SRCB) - 1));
                stage2[off] = ((const float2*)g)[src];
            }
        }
        __syncthreads();
        int a = sb[b][nid] - lo, bnd = sb[b][nid + 1] - lo;
        for (int j = a + half; j < bnd; j += 2) {
            if (j < CAP) acc += stage[j * 2 + c];
            else {  // fallback (expected never: span <= ~1170)
                unsigned w = (unsigned)sorted[lo + j];
                int src = (int)(w & ((1u << SRCB) - 1));
                acc += g[2 * (size_t)src + c];
            }
        }
        __syncthreads();  // stage reuse
    }
    if (half == 1) sres[nid * 2 + c] = acc;
    __syncthreads();
    if (half == 0) sres[nid * 2 + c] += acc;
    __syncthreads();
    if (tid < NB) {
        int i = i0 + tid;
        if (i < n) {
            float d = dinv[i];
            float2 gi = ((const float2*)g)[i];
            float s0 = (sres[tid * 2] + gi.x) * d;
            float s1 = (sres[tid * 2 + 1] + gi.y) * d;
            float oc0 = 0.0f, oc1 = 0.0f, oc2 = 0.0f, oc3 = 0.0f;
            #pragma unroll
            for (int f = 0; f < 8; f++) {
                float h = fmaxf(s0 * W1[f] + s1 * W1[8 + f] + b1[f], 0.0f);
                oc0 += h * W2[4 * f];
                oc1 += h * W2[4 * f + 1];
                oc2 += h * W2[4 * f + 2];
                oc3 += h * W2[4 * f + 3];
            }
            float4 o;
            o.x = oc0 * d; o.y = oc1 * d; o.z = oc2 * d; o.w = oc3 * d;
            ((float4*)hs2)[i] = o;
        }
    }
}

__global__ __launch_bounds__(512) void agg2s_kernel(
    const int* __restrict__ sorted, const int* __restrict__ runStart,
    const float* __restrict__ hs2, const float* __restrict__ dinv,
    const float* __restrict__ b2, float* __restrict__ out, int n) {
    __shared__ float4 stage4[CAP];
    __shared__ int sb[BC][NB + 1];
    float* stage = (float*)stage4;
    int tid = threadIdx.x;
    int i0 = blockIdx.x * NB;
    int dp = i0 >> LPBIT, l0 = i0 & (PART - 1);
    for (int k = tid; k < BC * (NB + 1); k += 512) {
        int b = k / (NB + 1), idx = k - b * (NB + 1);
        sb[b][idx] = runStart[(size_t)(dp * BC + b) * RSTR + l0 + idx];
    }
    int nid = tid >> 2, c = tid & 3;
    float acc = 0.0f;
    __syncthreads();
    #pragma unroll
    for (int b = 0; b < BC; b++) {
        int lo = sb[b][0], hi = sb[b][NB];
        for (int e = lo + tid; e < hi; e += 512) {
            int off = e - lo;
            if (off < CAP) {
                unsigned w = (unsigned)sorted[e];
                int src = (int)(w & ((1u << SRCB) - 1));
                stage4[off] = ((const float4*)hs2)[src];
            }
        }
        __syncthreads();
        int a = sb[b][nid] - lo, bnd = sb[b][nid + 1] - lo;
        for (int j = a; j < bnd; j++) {
            if (j < CAP) acc += stage[j * 4 + c];
            else {  // fallback (expected never)
                unsigned w = (unsigned)sorted[lo + j];
                int src = (int)(w & ((1u << SRCB) - 1));
                acc += hs2[4 * (size_t)src + c];
            }
        }
        __syncthreads();  // stage reuse
    }
    int i = i0 + nid;
    if (i < n) {
        float d = dinv[i];
        float hv = hs2[4 * (size_t)i + c];
        out[4 * (size_t)i + c] = d * (acc + hv) + b2[c];
    }
}

extern "C" void kernel_launch(void* const* d_in, const int* in_sizes, int n_in,
                              void* d_out, int out_size, void* d_ws, size_t ws_size,
                              hipStream_t stream) {
    const float* x   = (const float*)d_in[0];
    const int*   ei  = (const int*)d_in[1];
    const float* W1  = (const float*)d_in[2];
    const float* b1  = (const float*)d_in[3];
    const float* W2  = (const float*)d_in[4];
    const float* b2  = (const float*)d_in[5];
    float* out = (float*)d_out;

    const int n = in_sizes[0] / 2;  // x is [N,2]
    const int E = in_sizes[1] / 2;  // edge_index is [2,E]
    const int* src = ei;
    const int* dst = ei + E;

    const int P  = (n + PART - 1) >> LPBIT;  // 98
    const int B1 = (E + EPB - 1) / EPB;      // 782

    int* ws = (int*)d_ws;
    int* colTotal = ws;                                      // 1024
    int* colStart = ws + 1024;                               // 1024
    int* cntmatA  = ws + 2048;                               // B1*P
    size_t cmsz = (((size_t)B1 * P) + 3) & ~(size_t)3;
    int* runStart = cntmatA + cmsz;                          // P*BC*RSTR
    size_t rssz = (((size_t)P * BC * RSTR) + 3) & ~(size_t)3;
    unsigned* packed = (unsigned*)(runStart + rssz);         // E
    int* sorted = (int*)(packed + E);                        // E
    // packed region is dead after localC; overlay node buffers (7*nd <= E):
    size_t nd = (size_t)P << LPBIT;                          // 200704
    float* dinv = (float*)packed;                            // nd
    float* g    = dinv + nd;                                 // 2*nd
    float* hs2  = g + 2 * nd;                                // 4*nd

    const int gN = (n + 511) / 512;
    const int gB = (n + NB - 1) / NB;

    countA_kernel    <<<B1, 512, 0, stream>>>(dst, cntmatA, E, P);
    colscanA_kernel  <<<P, 256, 0, stream>>>(cntmatA, colTotal, B1, P);
    totalscanA_kernel<<<1, 256, 0, stream>>>(colTotal, colStart, P, E);
    scatterA_kernel  <<<B1, 512, 0, stream>>>(src, dst, cntmatA, colStart, packed, E, P);
    localC_kernel    <<<P * BC, 512, 0, stream>>>(packed, colStart, runStart, sorted);
    dinvg_kernel     <<<gN, 512, 0, stream>>>(runStart, x, dinv, g, n);
    agg1s_kernel     <<<gB, 512, 0, stream>>>(sorted, runStart, g, dinv, W1, b1, W2, hs2, n);
    agg2s_kernel     <<<gB, 512, 0, stream>>>(sorted, runStart, hs2, dinv, b2, out, n);
}